// Round 13
// baseline (620.763 us; speedup 1.0000x reference)
//
#include <hip/hip_runtime.h>
#include <cstdint>

typedef unsigned short u16;
typedef __attribute__((ext_vector_type(8))) short short8;
typedef __attribute__((ext_vector_type(4))) float floatx4;
typedef __attribute__((ext_vector_type(4))) float f4;

#define NQP   64
#define MQP   128
#define NP    2080
#define NHH   8192
#define NOUT  10464   /* 2080 + 64 + 8192 + 128 */
#define NOUTP 10496   /* padded to 82*128 */

__device__ __forceinline__ float b2f(u16 u) {
  union { unsigned int i; float f; } v; v.i = ((unsigned int)u) << 16; return v.f;
}
__device__ __forceinline__ u16 f2b(float f) {
  union { float f; unsigned int i; } v; v.f = f;
  unsigned int r = v.i + 0x7fffu + ((v.i >> 16) & 1u);
  return (u16)(r >> 16);
}

// ---------------------------------------------------------------------------
// dtype detector (flag=1 -> inputs are f32)
// ---------------------------------------------------------------------------
__global__ __launch_bounds__(256) void detect_dtype(const u16* __restrict__ w,
                                                    int* __restrict__ flag) {
  __shared__ int cnt;
  if (threadIdx.x == 0) cnt = 0;
  __syncthreads();
  int c = 0;
  for (int i = threadIdx.x; i < 16384; i += 256) {
    const int e = (w[i] >> 7) & 0xFF;
    if (e >= 130 || e <= 90) ++c;
  }
  atomicAdd(&cnt, c);
  __syncthreads();
  if (threadIdx.x == 0) flag[0] = (cnt > 3000) ? 1 : 0;
}

__device__ __forceinline__ u16 load_elem_bf16(const void* p, size_t idx, int isf32) {
  return isf32 ? f2b(((const float*)p)[idx]) : ((const u16*)p)[idx];
}

__global__ __launch_bounds__(256) void convert_bf16(const void* __restrict__ in,
                                                    u16* __restrict__ out, int n,
                                                    const int* __restrict__ flag) {
  const int isf = flag[0];
  for (int i = blockIdx.x * 256 + threadIdx.x; i < n; i += gridDim.x * 256)
    out[i] = load_elem_bf16(in, i, isf);
}

// all three biases in one launch
__global__ __launch_bounds__(256) void conv_biases(const void* __restrict__ b1,
                                                   const void* __restrict__ b2,
                                                   const void* __restrict__ b3,
                                                   float* __restrict__ bf1,
                                                   float* __restrict__ bf2,
                                                   float* __restrict__ bf3,
                                                   const int* __restrict__ flag) {
  const int isf = flag[0];
  const int i = blockIdx.x * 256 + threadIdx.x;
  if (i < 1024) {
    bf1[i] = isf ? ((const float*)b1)[i] : b2f(((const u16*)b1)[i]);
  } else if (i < 2048) {
    const int j = i - 1024;
    bf2[j] = isf ? ((const float*)b2)[j] : b2f(((const u16*)b2)[j]);
  } else if (i < 2048 + NOUT) {
    const int j = i - 2048;
    bf3[j] = isf ? ((const float*)b3)[j] : b2f(((const u16*)b3)[j]);
  }
}

// ---------------------------------------------------------------------------
// All three weight transposes in one launch.
// ---------------------------------------------------------------------------
__global__ __launch_bounds__(256) void transpose_all(const void* __restrict__ W1,
                                                     const void* __restrict__ W2,
                                                     const void* __restrict__ W3,
                                                     u16* __restrict__ W1t,
                                                     u16* __restrict__ W2t,
                                                     u16* __restrict__ W3t,
                                                     const int* __restrict__ flag) {
  const int bx = blockIdx.x, by = blockIdx.y;
  const void* in; u16* out; int K, N, Npad, bxo;
  if (bx < 32)      { in = W1; out = W1t; K = 512;  N = 1024; Npad = 1024;  bxo = 0;
                      if (by >= 16) return; }
  else if (bx < 64) { in = W2; out = W2t; K = 1024; N = 1024; Npad = 1024;  bxo = 32; }
  else              { in = W3; out = W3t; K = 1024; N = NOUT; Npad = NOUTP; bxo = 64; }
  __shared__ u16 tile[32][33];
  const int isf = flag[0];
  const int n0 = (bx - bxo) * 32, k0 = by * 32;
  const int tx = threadIdx.x & 31, ty = threadIdx.x >> 5;
#pragma unroll
  for (int i = 0; i < 4; ++i) {
    const int k = k0 + ty + 8 * i, n = n0 + tx;
    tile[ty + 8 * i][tx] = (n < N) ? load_elem_bf16(in, (size_t)k * N + n, isf) : (u16)0;
  }
  __syncthreads();
#pragma unroll
  for (int i = 0; i < 4; ++i) {
    const int n = n0 + ty + 8 * i, k = k0 + tx;
    if (n < Npad) out[(size_t)n * K + k] = tile[tx][ty + 8 * i];
  }
}

// ---------------------------------------------------------------------------
// GEMM (m97-style 128x128 tile).
// EPI==0: relu, split-store bf16 hi+lo.  EPI==1: store f32.  EPI==2: relu, hi only.
// ---------------------------------------------------------------------------
__device__ __forceinline__ void gload_lds16(const u16* g, u16* l) {
  __builtin_amdgcn_global_load_lds((const __attribute__((address_space(1))) void*)g,
                                   (__attribute__((address_space(3))) void*)l, 16, 0, 0);
}

template <int EPI, bool HAS_LO>
__global__ __launch_bounds__(256) void gemm_bt(const u16* __restrict__ Ahi, const u16* __restrict__ Alo,
                                               const u16* __restrict__ Bt,  const float* __restrict__ bias,
                                               u16* __restrict__ Chi, u16* __restrict__ Clo,
                                               float* __restrict__ Cf,
                                               int M, int N, int K) {
  __shared__ __align__(16) u16 lA[128 * 32];
  __shared__ __align__(16) u16 lAlo[128 * 32];
  __shared__ __align__(16) u16 lB[128 * 32];
  const int tile_n = blockIdx.x * 128;
  const int tile_m = blockIdx.y * 128;
  const int lane = threadIdx.x & 63;
  const int wv   = threadIdx.x >> 6;
  const int wm = (wv & 1) * 64;
  const int wn = (wv >> 1) * 64;
  const int sr = lane >> 2;
  const int sk = (lane & 3) * 8;
  floatx4 acc[4][4] = {};

  for (int k0 = 0; k0 < K; k0 += 32) {
#pragma unroll
    for (int it = 0; it < 2; ++it) {
      const int slot = it * 4 + wv;
      const int r = slot * 16 + sr;
      gload_lds16(Ahi + (size_t)(tile_m + r) * K + k0 + sk, lA + slot * 512);
      if (HAS_LO)
        gload_lds16(Alo + (size_t)(tile_m + r) * K + k0 + sk, lAlo + slot * 512);
      gload_lds16(Bt + (size_t)(tile_n + r) * K + k0 + sk, lB + slot * 512);
    }
    __syncthreads();
    const int ro = lane & 15;
    const int qo = (lane >> 4) * 8;
    short8 af[4], bfr[4], al[4];
#pragma unroll
    for (int i = 0; i < 4; ++i) af[i] = *(const short8*)(lA + (wm + i * 16 + ro) * 32 + qo);
#pragma unroll
    for (int j = 0; j < 4; ++j) bfr[j] = *(const short8*)(lB + (wn + j * 16 + ro) * 32 + qo);
    if (HAS_LO) {
#pragma unroll
      for (int i = 0; i < 4; ++i) al[i] = *(const short8*)(lAlo + (wm + i * 16 + ro) * 32 + qo);
    }
#pragma unroll
    for (int i = 0; i < 4; ++i)
#pragma unroll
      for (int j = 0; j < 4; ++j) {
        acc[i][j] = __builtin_amdgcn_mfma_f32_16x16x32_bf16(af[i], bfr[j], acc[i][j], 0, 0, 0);
        if (HAS_LO)
          acc[i][j] = __builtin_amdgcn_mfma_f32_16x16x32_bf16(al[i], bfr[j], acc[i][j], 0, 0, 0);
      }
    __syncthreads();
  }

  const int colb = tile_n + wn + (lane & 15);
  const int rowb = tile_m + wm + (lane >> 4) * 4;
#pragma unroll
  for (int j = 0; j < 4; ++j) {
    const int col = colb + j * 16;
    const float bv = (col < N) ? bias[col] : 0.f;
#pragma unroll
    for (int i = 0; i < 4; ++i) {
#pragma unroll
      for (int v = 0; v < 4; ++v) {
        const int row = rowb + i * 16 + v;
        float val = acc[i][j][v] + bv;
        if (EPI == 0) {
          val = fmaxf(val, 0.f);
          const u16 hi = f2b(val);
          const float lo = val - b2f(hi);
          Chi[(size_t)row * N + col] = hi;
          Clo[(size_t)row * N + col] = f2b(lo);
        } else if (EPI == 2) {
          val = fmaxf(val, 0.f);
          Chi[(size_t)row * N + col] = f2b(val);
        } else {
          if (col < N) Cf[(size_t)row * N + col] = val;
        }
      }
    }
  }
}

// ---------------------------------------------------------------------------
// 64x64-tile GEMM for the two small square GEMMs (M=N=1024): 256 blocks
// so all 256 CUs are busy (the 128^2 version left 75% idle).
// ---------------------------------------------------------------------------
template <int EPI, bool HAS_LO>
__global__ __launch_bounds__(256) void gemm_bt64(const u16* __restrict__ Ahi, const u16* __restrict__ Alo,
                                                 const u16* __restrict__ Bt,  const float* __restrict__ bias,
                                                 u16* __restrict__ Chi, u16* __restrict__ Clo,
                                                 int N, int K) {
  __shared__ __align__(16) u16 lA[64 * 32];
  __shared__ __align__(16) u16 lAlo[64 * 32];
  __shared__ __align__(16) u16 lB[64 * 32];
  const int tile_n = blockIdx.x * 64;
  const int tile_m = blockIdx.y * 64;
  const int lane = threadIdx.x & 63;
  const int wv   = threadIdx.x >> 6;
  const int wm = (wv & 1) * 32;
  const int wn = (wv >> 1) * 32;
  const int sr = lane >> 2;
  const int sk = (lane & 3) * 8;
  floatx4 acc[2][2] = {};

  for (int k0 = 0; k0 < K; k0 += 32) {
    {
      const int r = wv * 16 + sr;            // slot wv covers rows wv*16..+15
      gload_lds16(Ahi + (size_t)(tile_m + r) * K + k0 + sk, lA + wv * 512);
      if (HAS_LO)
        gload_lds16(Alo + (size_t)(tile_m + r) * K + k0 + sk, lAlo + wv * 512);
      gload_lds16(Bt + (size_t)(tile_n + r) * K + k0 + sk, lB + wv * 512);
    }
    __syncthreads();
    const int ro = lane & 15;
    const int qo = (lane >> 4) * 8;
    short8 af[2], bfr[2], al[2];
#pragma unroll
    for (int i = 0; i < 2; ++i) af[i] = *(const short8*)(lA + (wm + i * 16 + ro) * 32 + qo);
#pragma unroll
    for (int j = 0; j < 2; ++j) bfr[j] = *(const short8*)(lB + (wn + j * 16 + ro) * 32 + qo);
    if (HAS_LO) {
#pragma unroll
      for (int i = 0; i < 2; ++i) al[i] = *(const short8*)(lAlo + (wm + i * 16 + ro) * 32 + qo);
    }
#pragma unroll
    for (int i = 0; i < 2; ++i)
#pragma unroll
      for (int j = 0; j < 2; ++j) {
        acc[i][j] = __builtin_amdgcn_mfma_f32_16x16x32_bf16(af[i], bfr[j], acc[i][j], 0, 0, 0);
        if (HAS_LO)
          acc[i][j] = __builtin_amdgcn_mfma_f32_16x16x32_bf16(al[i], bfr[j], acc[i][j], 0, 0, 0);
      }
    __syncthreads();
  }

  const int colb = tile_n + wn + (lane & 15);
  const int rowb = tile_m + wm + (lane >> 4) * 4;
#pragma unroll
  for (int j = 0; j < 2; ++j) {
    const int col = colb + j * 16;
    const float bv = bias[col];
#pragma unroll
    for (int i = 0; i < 2; ++i) {
#pragma unroll
      for (int v = 0; v < 4; ++v) {
        const int row = rowb + i * 16 + v;
        float val = acc[i][j][v] + bv;
        val = fmaxf(val, 0.f);
        const u16 hi = f2b(val);
        Chi[(size_t)row * N + col] = hi;
        if (EPI == 0) {
          const float lo = val - b2f(hi);
          Clo[(size_t)row * N + col] = f2b(lo);
        }
      }
    }
  }
}

// ---------------------------------------------------------------------------
// QP helpers
// ---------------------------------------------------------------------------
__device__ __forceinline__ f4 ld4s(const float* p) { return *(const f4*)p; }
__device__ __forceinline__ float dot4(f4 a, f4 b) {
  return fmaf(a.x, b.x, fmaf(a.y, b.y, fmaf(a.z, b.z, a.w * b.w)));
}
__device__ __forceinline__ float rdlane(float v, int lane) {
  return __int_as_float(__builtin_amdgcn_readlane(__float_as_int(v), lane));
}
// XOR-swizzled float-index of f4 group g in row m (row stride 64 floats).
__device__ __forceinline__ int hQ(int m, int g) {
  return (m << 6) + (((g ^ (m & 15))) << 2);
}

// ---------------------------------------------------------------------------
// Per-batch QP solver, R17: ONE WAVE PER PROBLEM (64-thread blocks, grid
// 1024).  The R5 structure's binder is barrier rendezvous across 4 waves
// (VALU work ~66us vs ~210us loop wall; all pipes <30%).  Wave-local
// execution removes every barrier from the hot loops:
//   - lambda/x/xbar/rhs/q/b in REGISTERS, broadcast via v_readlane (2-cyc
//     VALU, ordered by program order within the wave; no DS, no sync)
//   - Minv as M[64] per lane (lane i owns row i); GJ pivot row via
//     readlane with the k-loop fully unrolled (all indices static ->
//     no scratch per rule #20)
//   - H in LDS (32 KB, hQ swizzle); phase-B column reads are conflict-free
//     b32 (swizzle maps 64 lanes to 64 distinct words per row)
//   - __syncthreads only in setup (1-wave block: waitcnt only, no rendezvous)
// __launch_bounds__(64,1) -> 256+ VGPR budget (R15 proved arg 2 is honored;
// peak need ~150).  LDS 32 KB -> 4-5 blocks/CU.
// FAIL-CHECKS: VGPR must be >>64 and FETCH ~100 MB; VGPR=64 + GB FETCH =
// the R6/R8/R9 remat trap -> revert to R5 config and stop.
// ---------------------------------------------------------------------------
__global__ __launch_bounds__(64, 1) void qp_wave(const float* __restrict__ outbuf,
                                                 void* __restrict__ xs,
                                                 const int* __restrict__ flag) {
  __shared__ __align__(16) float H_s[8192];   // setup: Ld 64x68; loop: H swizzled
  const int l = threadIdx.x;
  const int isf = flag[0];
  const float* ob = outbuf + (size_t)blockIdx.x * NOUT;

  // ---- setup: dense L (stride 68, zero-padded) ----
  float* Ld = H_s;
  for (int e = l; e < 4352; e += 64) Ld[e] = 0.f;
  __syncthreads();
  for (int e = l; e < NP; e += 64) {
    int i = (int)((sqrtf(8.f * (float)e + 1.f) - 1.f) * 0.5f);
    while ((i + 1) * (i + 2) / 2 <= e) ++i;
    while (i * (i + 1) / 2 > e) --i;
    const int j = e - i * (i + 1) / 2;   // j <= i
    Ld[i * 68 + j] = ob[e];
  }
  __syncthreads();
  {
    const float xv = Ld[l * 68 + l];
    Ld[l * 68 + l] = 0.1f + (fmaxf(xv, 0.f) + log1pf(expf(-fabsf(xv))));
  }
  __syncthreads();

  const float qreg = ob[NP + l];                    // q_l
  const float br0  = ob[NP + NQP + NHH + l];        // b_l
  const float br1  = ob[NP + NQP + NHH + 64 + l];   // b_{l+64}

  // ---- P = L L^T : lane l owns row l -> M[64] ----
  float M[64];
  {
    f4 Lr[16];
#pragma unroll
    for (int g = 0; g < 16; ++g) Lr[g] = ld4s(&Ld[l * 68 + 4 * g]);
#pragma unroll
    for (int j = 0; j < 64; ++j) {
      float sa = 0.f, sb = 0.f;
#pragma unroll
      for (int g = 0; g < 16; g += 2) {
        sa += dot4(Lr[g],     ld4s(&Ld[j * 68 + 4 * g]));
        sb += dot4(Lr[g + 1], ld4s(&Ld[j * 68 + 4 * g + 4]));
      }
      M[j] = sa + sb;
    }
  }
  __syncthreads();   // done with Ld

  // ---- H into LDS (swizzled f32) ----
  for (int e = l; e < NHH; e += 64) {
    const int m = e >> 6, n = e & 63;
    H_s[hQ(m, n >> 2) + (n & 3)] = ob[NP + NQP + e];
  }
  __syncthreads();

  // precomputed LDS addresses (constant across iterations)
  int ha[16];   // row l, f4 group g   (row l+64 = ha[g] + 4096)
#pragma unroll
  for (int g = 0; g < 16; ++g) ha[g] = hQ(l, g);
  int ca[16];   // column l, row with (m & 15) == p : element = ca[p] + m*64
#pragma unroll
  for (int p = 0; p < 16; ++p) ca[p] = (((l >> 2) ^ p) << 2) + (l & 3);

  // ---- power iteration: 10 v-updates, pass 11 computes Hv for tau ----
  float v = 0.125f;
  float s0 = 0.f, s1 = 0.f;
  for (int pi = 0; pi < 11; ++pi) {
    float a0 = 0.f, a1 = 0.f, b0 = 0.f, b1 = 0.f;
#pragma unroll
    for (int g = 0; g < 16; g += 2) {
      const f4 h0 = ld4s(&H_s[ha[g]]);
      const f4 h2 = ld4s(&H_s[ha[g + 1]]);
      const f4 h1 = ld4s(&H_s[ha[g] + 4096]);
      const f4 h3 = ld4s(&H_s[ha[g + 1] + 4096]);
      const float x0 = rdlane(v, 4 * g + 0), x1 = rdlane(v, 4 * g + 1);
      const float x2 = rdlane(v, 4 * g + 2), x3 = rdlane(v, 4 * g + 3);
      const float x4 = rdlane(v, 4 * g + 4), x5 = rdlane(v, 4 * g + 5);
      const float x6 = rdlane(v, 4 * g + 6), x7 = rdlane(v, 4 * g + 7);
      a0 = fmaf(h0.x, x0, fmaf(h0.y, x1, fmaf(h0.z, x2, fmaf(h0.w, x3, a0))));
      b0 = fmaf(h2.x, x4, fmaf(h2.y, x5, fmaf(h2.z, x6, fmaf(h2.w, x7, b0))));
      a1 = fmaf(h1.x, x0, fmaf(h1.y, x1, fmaf(h1.z, x2, fmaf(h1.w, x3, a1))));
      b1 = fmaf(h3.x, x4, fmaf(h3.y, x5, fmaf(h3.z, x6, fmaf(h3.w, x7, b1))));
    }
    s0 = a0 + b0;   // (H v)_l
    s1 = a1 + b1;   // (H v)_{l+64}
    if (pi == 10) break;
    // u = H^T (H v) : lane l owns column l (conflict-free b32 via swizzle)
    float u0 = 0.f, u1 = 0.f, u2 = 0.f, u3 = 0.f;
#pragma unroll
    for (int m = 0; m < 64; m += 4) {
      u0 = fmaf(H_s[ca[(m + 0) & 15] + (m + 0) * 64], rdlane(s0, m + 0), u0);
      u1 = fmaf(H_s[ca[(m + 1) & 15] + (m + 1) * 64], rdlane(s0, m + 1), u1);
      u2 = fmaf(H_s[ca[(m + 2) & 15] + (m + 2) * 64], rdlane(s0, m + 2), u2);
      u3 = fmaf(H_s[ca[(m + 3) & 15] + (m + 3) * 64], rdlane(s0, m + 3), u3);
    }
#pragma unroll
    for (int m = 0; m < 64; m += 4) {
      u0 = fmaf(H_s[ca[(m + 0) & 15] + (m + 64) * 64], rdlane(s1, m + 0), u0);
      u1 = fmaf(H_s[ca[(m + 1) & 15] + (m + 65) * 64], rdlane(s1, m + 1), u1);
      u2 = fmaf(H_s[ca[(m + 2) & 15] + (m + 66) * 64], rdlane(s1, m + 2), u2);
      u3 = fmaf(H_s[ca[(m + 3) & 15] + (m + 67) * 64], rdlane(s1, m + 3), u3);
    }
    const float u = (u0 + u1) + (u2 + u3);
    float ss = u * u;
#pragma unroll
    for (int o = 1; o <= 32; o <<= 1) ss += __shfl_xor(ss, o, 64);
    v = u / (sqrtf(ss) + 1e-12f);
  }
  // ---- tau = 0.9 / (||H v|| + 1e-6) ----
  float tau;
  {
    float ss = s0 * s0 + s1 * s1;
#pragma unroll
    for (int o = 1; o <= 32; o <<= 1) ss += __shfl_xor(ss, o, 64);
    tau = 0.9f / (sqrtf(ss) + 1e-6f);
  }

  // ---- M = I + tau*P ----
#pragma unroll
  for (int j = 0; j < 64; ++j)
    M[j] = tau * M[j] + ((j == l) ? 1.0f : 0.0f);

  // ---- Gauss-Jordan inversion, wave-local (pivot row via readlane) ----
#pragma unroll
  for (int k = 0; k < 64; ++k) {
    const float d  = 1.0f / rdlane(M[k], k);
    const float fd = M[k] * d;            // own column-k element * d
    const bool piv = (l == k);
#pragma unroll
    for (int j = 0; j < 64; ++j) {
      if (j == k) continue;
      const float pr = rdlane(M[j], k);   // pivot row element j (pre-update)
      M[j] = piv ? (pr * d) : fmaf(-fd, pr, M[j]);
    }
    M[k] = piv ? d : -fd;
  }

  // ---- c0 = tau * (Minv q) ----
  float c0;
  {
    float c0a = 0.f, c0b = 0.f, c0c = 0.f, c0d = 0.f;
#pragma unroll
    for (int j = 0; j < 64; j += 4) {
      c0a = fmaf(M[j + 0], rdlane(qreg, j + 0), c0a);
      c0b = fmaf(M[j + 1], rdlane(qreg, j + 1), c0b);
      c0c = fmaf(M[j + 2], rdlane(qreg, j + 2), c0c);
      c0d = fmaf(M[j + 3], rdlane(qreg, j + 3), c0d);
    }
    c0 = tau * ((c0a + c0b) + (c0c + c0d));
  }

  // ---- PDHG (50 iters), ZERO barriers ----
  float xb = 0.f, xp = 0.f, xpr = 0.f, lam0 = 0.f, lam1 = 0.f;
  for (int it = 0; it < 50; ++it) {
    // A: lam = relu(lam - tau*(H xbar + b))  [rows l, l+64; xb via readlane]
    float a0 = 0.f, a1 = 0.f, b0 = 0.f, b1 = 0.f;
#pragma unroll
    for (int g = 0; g < 16; g += 2) {
      const f4 h0 = ld4s(&H_s[ha[g]]);
      const f4 h2 = ld4s(&H_s[ha[g + 1]]);
      const f4 h1 = ld4s(&H_s[ha[g] + 4096]);
      const f4 h3 = ld4s(&H_s[ha[g + 1] + 4096]);
      const float x0 = rdlane(xb, 4 * g + 0), x1 = rdlane(xb, 4 * g + 1);
      const float x2 = rdlane(xb, 4 * g + 2), x3 = rdlane(xb, 4 * g + 3);
      const float x4 = rdlane(xb, 4 * g + 4), x5 = rdlane(xb, 4 * g + 5);
      const float x6 = rdlane(xb, 4 * g + 6), x7 = rdlane(xb, 4 * g + 7);
      a0 = fmaf(h0.x, x0, fmaf(h0.y, x1, fmaf(h0.z, x2, fmaf(h0.w, x3, a0))));
      b0 = fmaf(h2.x, x4, fmaf(h2.y, x5, fmaf(h2.z, x6, fmaf(h2.w, x7, b0))));
      a1 = fmaf(h1.x, x0, fmaf(h1.y, x1, fmaf(h1.z, x2, fmaf(h1.w, x3, a1))));
      b1 = fmaf(h3.x, x4, fmaf(h3.y, x5, fmaf(h3.z, x6, fmaf(h3.w, x7, b1))));
    }
    lam0 = fmaxf(lam0 - tau * ((a0 + b0) + br0), 0.f);
    lam1 = fmaxf(lam1 - tau * ((a1 + b1) + br1), 0.f);
    // B: u_l = sum_m H[m][l] * lam_m   [column l, lam via readlane]
    float u0 = 0.f, u1 = 0.f, u2 = 0.f, u3 = 0.f;
#pragma unroll
    for (int m = 0; m < 64; m += 4) {
      u0 = fmaf(H_s[ca[(m + 0) & 15] + (m + 0) * 64], rdlane(lam0, m + 0), u0);
      u1 = fmaf(H_s[ca[(m + 1) & 15] + (m + 1) * 64], rdlane(lam0, m + 1), u1);
      u2 = fmaf(H_s[ca[(m + 2) & 15] + (m + 2) * 64], rdlane(lam0, m + 2), u2);
      u3 = fmaf(H_s[ca[(m + 3) & 15] + (m + 3) * 64], rdlane(lam0, m + 3), u3);
    }
#pragma unroll
    for (int m = 0; m < 64; m += 4) {
      u0 = fmaf(H_s[ca[(m + 0) & 15] + (m + 64) * 64], rdlane(lam1, m + 0), u0);
      u1 = fmaf(H_s[ca[(m + 1) & 15] + (m + 65) * 64], rdlane(lam1, m + 1), u1);
      u2 = fmaf(H_s[ca[(m + 2) & 15] + (m + 66) * 64], rdlane(lam1, m + 2), u2);
      u3 = fmaf(H_s[ca[(m + 3) & 15] + (m + 67) * 64], rdlane(lam1, m + 3), u3);
    }
    const float u = (u0 + u1) + (u2 + u3);
    // C: rhs lane-local; xn = Minv*rhs - c0 (rhs via readlane)
    const float rhs = xp + tau * u;
    float xa = 0.f, xbq = 0.f, xc = 0.f, xd = 0.f;
#pragma unroll
    for (int j = 0; j < 64; j += 4) {
      xa  = fmaf(M[j + 0], rdlane(rhs, j + 0), xa);
      xbq = fmaf(M[j + 1], rdlane(rhs, j + 1), xbq);
      xc  = fmaf(M[j + 2], rdlane(rhs, j + 2), xc);
      xd  = fmaf(M[j + 3], rdlane(rhs, j + 3), xd);
    }
    const float xn = ((xa + xbq) + (xc + xd)) - c0;
    xp = xn; xb = 2.f * xn - xpr; xpr = xn;
  }

  {
    const size_t oi = (size_t)blockIdx.x * NQP + l;
    if (isf) ((float*)xs)[oi] = xpr;
    else     ((u16*)xs)[oi]   = f2b(xpr);
  }
}

// ---------------------------------------------------------------------------
extern "C" void kernel_launch(void* const* d_in, const int* in_sizes, int n_in,
                              void* d_out, int out_size, void* d_ws, size_t ws_size,
                              hipStream_t stream) {
  const void* x  = d_in[0];
  const void* W1 = d_in[1];
  const void* b1 = d_in[2];
  const void* W2 = d_in[3];
  const void* b2 = d_in[4];
  const void* W3 = d_in[5];
  const void* b3 = d_in[6];

  char* ws = (char*)d_ws;
  size_t off = 0;
  auto take = [&](size_t bytes) -> char* {
    char* r = ws + off;
    off += (bytes + 255) & ~(size_t)255;
    return r;
  };
  int*   flag = (int*)take(256);
  float* bf1  = (float*)take(1024 * 4);
  float* bf2  = (float*)take(1024 * 4);
  float* bf3  = (float*)take((size_t)NOUT * 4);
  u16*   W3t  = (u16*)take((size_t)NOUTP * 1024 * 2);
  u16*   h2hi = (u16*)take(1024ull * 1024 * 2);
  char*  region = take(1024ull * NOUT * 4);   // outf, overlaid below
  float* outf = (float*)region;
  u16* xb   = (u16*)(region + 0);                 // 1 MB
  u16* W1t  = (u16*)(region + (1u << 20));        // 1 MB
  u16* W2t  = (u16*)(region + (2u << 20));        // 2 MB
  u16* h1hi = (u16*)(region + (4u << 20));        // 2 MB
  u16* h1lo = (u16*)(region + (6u << 20));        // 2 MB
  (void)ws_size; (void)in_sizes; (void)n_in; (void)out_size;

  detect_dtype<<<dim3(1), 256, 0, stream>>>((const u16*)W1, flag);

  convert_bf16<<<dim3(512), 256, 0, stream>>>(x, xb, 1024 * 512, flag);
  conv_biases<<<dim3(49), 256, 0, stream>>>(b1, b2, b3, bf1, bf2, bf3, flag);
  transpose_all<<<dim3(392, 32), 256, 0, stream>>>(W1, W2, W3, W1t, W2t, W3t, flag);

  // GEMM1: h1 = relu(x @ W1 + b1), split store (hi+lo) — 64x64 tiles, 256 blocks
  gemm_bt64<0, false><<<dim3(16, 16), 256, 0, stream>>>(xb, nullptr, W1t, bf1,
                                                        h1hi, h1lo, 1024, 512);
  // GEMM2: h2 = relu((h1hi+h1lo) @ W2 + b2), hi only — 64x64 tiles, 256 blocks
  gemm_bt64<2, true><<<dim3(16, 16), 256, 0, stream>>>(h1hi, h1lo, W2t, bf2,
                                                       h2hi, nullptr, 1024, 1024);
  // GEMM3: out = h2hi @ W3 + b3 (single chain, f32 out)
  gemm_bt<1, false><<<dim3(NOUTP / 128, 8), 256, 0, stream>>>(h2hi, nullptr, W3t, bf3,
                                                              nullptr, nullptr, outf, 1024, NOUT, 1024);
  qp_wave<<<dim3(1024), 64, 0, stream>>>(outf, d_out, flag);
}

// Round 14
// 466.212 us; speedup vs baseline: 1.3315x; 1.3315x over previous
//
#include <hip/hip_runtime.h>
#include <cstdint>

typedef unsigned short u16;
typedef __attribute__((ext_vector_type(8))) short short8;
typedef __attribute__((ext_vector_type(4))) float floatx4;
typedef __attribute__((ext_vector_type(4))) float f4;

#define NQP   64
#define MQP   128
#define NP    2080
#define NHH   8192
#define NOUT  10464   /* 2080 + 64 + 8192 + 128 */
#define NOUTP 10496   /* padded to 82*128 */

__device__ __forceinline__ float b2f(u16 u) {
  union { unsigned int i; float f; } v; v.i = ((unsigned int)u) << 16; return v.f;
}
__device__ __forceinline__ u16 f2b(float f) {
  union { float f; unsigned int i; } v; v.f = f;
  unsigned int r = v.i + 0x7fffu + ((v.i >> 16) & 1u);
  return (u16)(r >> 16);
}

// ---------------------------------------------------------------------------
// dtype detector (flag=1 -> inputs are f32)
// ---------------------------------------------------------------------------
__global__ __launch_bounds__(256) void detect_dtype(const u16* __restrict__ w,
                                                    int* __restrict__ flag) {
  __shared__ int cnt;
  if (threadIdx.x == 0) cnt = 0;
  __syncthreads();
  int c = 0;
  for (int i = threadIdx.x; i < 16384; i += 256) {
    const int e = (w[i] >> 7) & 0xFF;
    if (e >= 130 || e <= 90) ++c;
  }
  atomicAdd(&cnt, c);
  __syncthreads();
  if (threadIdx.x == 0) flag[0] = (cnt > 3000) ? 1 : 0;
}

__device__ __forceinline__ u16 load_elem_bf16(const void* p, size_t idx, int isf32) {
  return isf32 ? f2b(((const float*)p)[idx]) : ((const u16*)p)[idx];
}

__global__ __launch_bounds__(256) void convert_bf16(const void* __restrict__ in,
                                                    u16* __restrict__ out, int n,
                                                    const int* __restrict__ flag) {
  const int isf = flag[0];
  for (int i = blockIdx.x * 256 + threadIdx.x; i < n; i += gridDim.x * 256)
    out[i] = load_elem_bf16(in, i, isf);
}

// all three biases in one launch
__global__ __launch_bounds__(256) void conv_biases(const void* __restrict__ b1,
                                                   const void* __restrict__ b2,
                                                   const void* __restrict__ b3,
                                                   float* __restrict__ bf1,
                                                   float* __restrict__ bf2,
                                                   float* __restrict__ bf3,
                                                   const int* __restrict__ flag) {
  const int isf = flag[0];
  const int i = blockIdx.x * 256 + threadIdx.x;
  if (i < 1024) {
    bf1[i] = isf ? ((const float*)b1)[i] : b2f(((const u16*)b1)[i]);
  } else if (i < 2048) {
    const int j = i - 1024;
    bf2[j] = isf ? ((const float*)b2)[j] : b2f(((const u16*)b2)[j]);
  } else if (i < 2048 + NOUT) {
    const int j = i - 2048;
    bf3[j] = isf ? ((const float*)b3)[j] : b2f(((const u16*)b3)[j]);
  }
}

// ---------------------------------------------------------------------------
// All three weight transposes in one launch.
// ---------------------------------------------------------------------------
__global__ __launch_bounds__(256) void transpose_all(const void* __restrict__ W1,
                                                     const void* __restrict__ W2,
                                                     const void* __restrict__ W3,
                                                     u16* __restrict__ W1t,
                                                     u16* __restrict__ W2t,
                                                     u16* __restrict__ W3t,
                                                     const int* __restrict__ flag) {
  const int bx = blockIdx.x, by = blockIdx.y;
  const void* in; u16* out; int K, N, Npad, bxo;
  if (bx < 32)      { in = W1; out = W1t; K = 512;  N = 1024; Npad = 1024;  bxo = 0;
                      if (by >= 16) return; }
  else if (bx < 64) { in = W2; out = W2t; K = 1024; N = 1024; Npad = 1024;  bxo = 32; }
  else              { in = W3; out = W3t; K = 1024; N = NOUT; Npad = NOUTP; bxo = 64; }
  __shared__ u16 tile[32][33];
  const int isf = flag[0];
  const int n0 = (bx - bxo) * 32, k0 = by * 32;
  const int tx = threadIdx.x & 31, ty = threadIdx.x >> 5;
#pragma unroll
  for (int i = 0; i < 4; ++i) {
    const int k = k0 + ty + 8 * i, n = n0 + tx;
    tile[ty + 8 * i][tx] = (n < N) ? load_elem_bf16(in, (size_t)k * N + n, isf) : (u16)0;
  }
  __syncthreads();
#pragma unroll
  for (int i = 0; i < 4; ++i) {
    const int n = n0 + ty + 8 * i, k = k0 + tx;
    if (n < Npad) out[(size_t)n * K + k] = tile[tx][ty + 8 * i];
  }
}

// ---------------------------------------------------------------------------
// GEMM (m97-style 128x128 tile).
// EPI==0: relu, split-store bf16 hi+lo.  EPI==1: store f32.  EPI==2: relu, hi only.
// ---------------------------------------------------------------------------
__device__ __forceinline__ void gload_lds16(const u16* g, u16* l) {
  __builtin_amdgcn_global_load_lds((const __attribute__((address_space(1))) void*)g,
                                   (__attribute__((address_space(3))) void*)l, 16, 0, 0);
}

template <int EPI, bool HAS_LO>
__global__ __launch_bounds__(256) void gemm_bt(const u16* __restrict__ Ahi, const u16* __restrict__ Alo,
                                               const u16* __restrict__ Bt,  const float* __restrict__ bias,
                                               u16* __restrict__ Chi, u16* __restrict__ Clo,
                                               float* __restrict__ Cf,
                                               int M, int N, int K) {
  __shared__ __align__(16) u16 lA[128 * 32];
  __shared__ __align__(16) u16 lAlo[128 * 32];
  __shared__ __align__(16) u16 lB[128 * 32];
  const int tile_n = blockIdx.x * 128;
  const int tile_m = blockIdx.y * 128;
  const int lane = threadIdx.x & 63;
  const int wv   = threadIdx.x >> 6;
  const int wm = (wv & 1) * 64;
  const int wn = (wv >> 1) * 64;
  const int sr = lane >> 2;
  const int sk = (lane & 3) * 8;
  floatx4 acc[4][4] = {};

  for (int k0 = 0; k0 < K; k0 += 32) {
#pragma unroll
    for (int it = 0; it < 2; ++it) {
      const int slot = it * 4 + wv;
      const int r = slot * 16 + sr;
      gload_lds16(Ahi + (size_t)(tile_m + r) * K + k0 + sk, lA + slot * 512);
      if (HAS_LO)
        gload_lds16(Alo + (size_t)(tile_m + r) * K + k0 + sk, lAlo + slot * 512);
      gload_lds16(Bt + (size_t)(tile_n + r) * K + k0 + sk, lB + slot * 512);
    }
    __syncthreads();
    const int ro = lane & 15;
    const int qo = (lane >> 4) * 8;
    short8 af[4], bfr[4], al[4];
#pragma unroll
    for (int i = 0; i < 4; ++i) af[i] = *(const short8*)(lA + (wm + i * 16 + ro) * 32 + qo);
#pragma unroll
    for (int j = 0; j < 4; ++j) bfr[j] = *(const short8*)(lB + (wn + j * 16 + ro) * 32 + qo);
    if (HAS_LO) {
#pragma unroll
      for (int i = 0; i < 4; ++i) al[i] = *(const short8*)(lAlo + (wm + i * 16 + ro) * 32 + qo);
    }
#pragma unroll
    for (int i = 0; i < 4; ++i)
#pragma unroll
      for (int j = 0; j < 4; ++j) {
        acc[i][j] = __builtin_amdgcn_mfma_f32_16x16x32_bf16(af[i], bfr[j], acc[i][j], 0, 0, 0);
        if (HAS_LO)
          acc[i][j] = __builtin_amdgcn_mfma_f32_16x16x32_bf16(al[i], bfr[j], acc[i][j], 0, 0, 0);
      }
    __syncthreads();
  }

  const int colb = tile_n + wn + (lane & 15);
  const int rowb = tile_m + wm + (lane >> 4) * 4;
#pragma unroll
  for (int j = 0; j < 4; ++j) {
    const int col = colb + j * 16;
    const float bv = (col < N) ? bias[col] : 0.f;
#pragma unroll
    for (int i = 0; i < 4; ++i) {
#pragma unroll
      for (int v = 0; v < 4; ++v) {
        const int row = rowb + i * 16 + v;
        float val = acc[i][j][v] + bv;
        if (EPI == 0) {
          val = fmaxf(val, 0.f);
          const u16 hi = f2b(val);
          const float lo = val - b2f(hi);
          Chi[(size_t)row * N + col] = hi;
          Clo[(size_t)row * N + col] = f2b(lo);
        } else if (EPI == 2) {
          val = fmaxf(val, 0.f);
          Chi[(size_t)row * N + col] = f2b(val);
        } else {
          if (col < N) Cf[(size_t)row * N + col] = val;
        }
      }
    }
  }
}

// ---------------------------------------------------------------------------
// 64x64-tile GEMM for the two small square GEMMs (M=N=1024): 256 blocks
// so all 256 CUs are busy (the 128^2 version left 75% idle).
// ---------------------------------------------------------------------------
template <int EPI, bool HAS_LO>
__global__ __launch_bounds__(256) void gemm_bt64(const u16* __restrict__ Ahi, const u16* __restrict__ Alo,
                                                 const u16* __restrict__ Bt,  const float* __restrict__ bias,
                                                 u16* __restrict__ Chi, u16* __restrict__ Clo,
                                                 int N, int K) {
  __shared__ __align__(16) u16 lA[64 * 32];
  __shared__ __align__(16) u16 lAlo[64 * 32];
  __shared__ __align__(16) u16 lB[64 * 32];
  const int tile_n = blockIdx.x * 64;
  const int tile_m = blockIdx.y * 64;
  const int lane = threadIdx.x & 63;
  const int wv   = threadIdx.x >> 6;
  const int wm = (wv & 1) * 32;
  const int wn = (wv >> 1) * 32;
  const int sr = lane >> 2;
  const int sk = (lane & 3) * 8;
  floatx4 acc[2][2] = {};

  for (int k0 = 0; k0 < K; k0 += 32) {
    {
      const int r = wv * 16 + sr;            // slot wv covers rows wv*16..+15
      gload_lds16(Ahi + (size_t)(tile_m + r) * K + k0 + sk, lA + wv * 512);
      if (HAS_LO)
        gload_lds16(Alo + (size_t)(tile_m + r) * K + k0 + sk, lAlo + wv * 512);
      gload_lds16(Bt + (size_t)(tile_n + r) * K + k0 + sk, lB + wv * 512);
    }
    __syncthreads();
    const int ro = lane & 15;
    const int qo = (lane >> 4) * 8;
    short8 af[2], bfr[2], al[2];
#pragma unroll
    for (int i = 0; i < 2; ++i) af[i] = *(const short8*)(lA + (wm + i * 16 + ro) * 32 + qo);
#pragma unroll
    for (int j = 0; j < 2; ++j) bfr[j] = *(const short8*)(lB + (wn + j * 16 + ro) * 32 + qo);
    if (HAS_LO) {
#pragma unroll
      for (int i = 0; i < 2; ++i) al[i] = *(const short8*)(lAlo + (wm + i * 16 + ro) * 32 + qo);
    }
#pragma unroll
    for (int i = 0; i < 2; ++i)
#pragma unroll
      for (int j = 0; j < 2; ++j) {
        acc[i][j] = __builtin_amdgcn_mfma_f32_16x16x32_bf16(af[i], bfr[j], acc[i][j], 0, 0, 0);
        if (HAS_LO)
          acc[i][j] = __builtin_amdgcn_mfma_f32_16x16x32_bf16(al[i], bfr[j], acc[i][j], 0, 0, 0);
      }
    __syncthreads();
  }

  const int colb = tile_n + wn + (lane & 15);
  const int rowb = tile_m + wm + (lane >> 4) * 4;
#pragma unroll
  for (int j = 0; j < 2; ++j) {
    const int col = colb + j * 16;
    const float bv = bias[col];
#pragma unroll
    for (int i = 0; i < 2; ++i) {
#pragma unroll
      for (int v = 0; v < 4; ++v) {
        const int row = rowb + i * 16 + v;
        float val = acc[i][j][v] + bv;
        val = fmaxf(val, 0.f);
        const u16 hi = f2b(val);
        Chi[(size_t)row * N + col] = hi;
        if (EPI == 0) {
          const float lo = val - b2f(hi);
          Clo[(size_t)row * N + col] = f2b(lo);
        }
      }
    }
  }
}

// ---------------------------------------------------------------------------
// QP helpers
// ---------------------------------------------------------------------------
__device__ __forceinline__ f4 ld4s(const float* p) { return *(const f4*)p; }
__device__ __forceinline__ void st4s(float* p, f4 v) { *(f4*)p = v; }
__device__ __forceinline__ float dot4(f4 a, f4 b) {
  return fmaf(a.x, b.x, fmaf(a.y, b.y, fmaf(a.z, b.z, a.w * b.w)));
}
__device__ __forceinline__ f4 shx4(f4 v, int m) {
  f4 r;
  r.x = __shfl_xor(v.x, m, 64); r.y = __shfl_xor(v.y, m, 64);
  r.z = __shfl_xor(v.z, m, 64); r.w = __shfl_xor(v.w, m, 64);
  return r;
}
// XOR-swizzled float-index of f4 group g in row m (row stride 64 floats).
__device__ __forceinline__ int hQ(int m, int g) {
  return (m << 6) + (((g ^ (m & 15))) << 2);
}

// ---------------------------------------------------------------------------
// Per-batch QP solver — R5 kernel verbatim, FINAL (best measured: 264 us).
// Eight structural axes tried, all regressions: R7 fewer-barriers=294,
// R11 bf16-H+8blk/CU=384, R12 tree-sum=330, R13 2-problem-ILP=328,
// R15 512-thread=354, R17 barrier-free 1-wave/problem=427 (proved barriers
// were NOT the binder — inter-wave latency hiding already covers them),
// R6/R8/R9 H-in-registers=remat trap.  Latency-bound serial PDHG at a
// verified sharp local optimum.
// ---------------------------------------------------------------------------
__global__ __launch_bounds__(256, 4) void qp_solve(const float* __restrict__ outbuf,
                                                   void* __restrict__ xs,
                                                   const int* __restrict__ flag) {
  __shared__ __align__(16) float H_s[8192];       // 32 KB (setup: Ld stride-68 + packed p)
  __shared__ __align__(16) float lam_s[128];      // also power-iter w staging
  __shared__ __align__(16) float b_s[128];
  __shared__ __align__(16) float part_s[4][64];
  __shared__ __align__(16) float rhs_s[64];
  __shared__ __align__(16) float xb_s[64];
  __shared__ __align__(16) float xp_s[64];
  __shared__ __align__(16) float q_s[64];
  __shared__ __align__(16) float buf2[2][64];
  __shared__ float tau_sh;

  const int t = threadIdx.x;
  const int w = t >> 6, l = t & 63;
  const int am = 32 * w + (l >> 1), as = l & 1;    // phase-A: row m, half s
  const int bg = l & 15, bc = l >> 4;              // phase-B: n-group, m-chunk
  const int ci = 16 * w + (l >> 2), cc = l & 3;    // M ownership: row i, col-slice c
  const int isf = flag[0];
  const float* ob = outbuf + (size_t)blockIdx.x * NOUT;

  // ---- setup: dense L (stride 68, zero-padded) + packed p ----
  float* Ld = H_s;                 // [0 .. 64*68) = 4352 floats
  float* ps = H_s + 4352;          // [4352 .. 6432)
  for (int e = t; e < 4352; e += 256) Ld[e] = 0.f;
  for (int e = t; e < NP; e += 256) ps[e] = ob[e];
  if (t < 64) q_s[t] = ob[NP + t];
  if (t >= 128 && t < 256) b_s[t - 128] = ob[NP + NQP + NHH + (t - 128)];
  __syncthreads();
  if (t < 64) {
    const int i = t + 1;
    const int d = i * (i + 1) / 2 - 1;
    const float xv = ps[d];
    ps[d] = 0.1f + (fmaxf(xv, 0.f) + log1pf(expf(-fabsf(xv))));
  }
  __syncthreads();
  for (int e = t; e < NP; e += 256) {
    int i = (int)((sqrtf(8.f * (float)e + 1.f) - 1.f) * 0.5f);
    while ((i + 1) * (i + 2) / 2 <= e) ++i;
    while (i * (i + 1) / 2 > e) --i;
    const int j = e - i * (i + 1) / 2;   // j <= i
    Ld[i * 68 + j] = ps[e];
  }
  __syncthreads();

  // ---- P = L L^T into registers M[16] (row ci, cols 16cc..16cc+15) ----
  float M[16];
#pragma unroll
  for (int jj = 0; jj < 16; ++jj) M[jj] = 0.f;
#pragma unroll
  for (int h = 0; h < 2; ++h) {
    f4 Lr[8];
#pragma unroll
    for (int g = 0; g < 8; ++g) Lr[g] = ld4s(&Ld[ci * 68 + (h * 8 + g) * 4]);
#pragma unroll
    for (int jj = 0; jj < 16; ++jj) {
      const int j = 16 * cc + jj;
      float s = 0.f;
#pragma unroll
      for (int g = 0; g < 8; ++g) s += dot4(Lr[g], ld4s(&Ld[j * 68 + (h * 8 + g) * 4]));
      M[jj] += s;
    }
  }
  __syncthreads();   // done with Ld/ps

  // ---- load H (swizzled f32), init power vector ----
  for (int e = t; e < NHH; e += 256) {
    const int m = e >> 6, n = e & 63;
    H_s[hQ(m, n >> 2) + (n & 3)] = ob[NP + NQP + e];
  }
  if (t < 64) xb_s[t] = 0.125f;
  __syncthreads();

  // ---- power iteration (10): v in xb_s, w staged in lam_s ----
  for (int pi = 0; pi < 10; ++pi) {
    {
      float s = 0.f;
#pragma unroll
      for (int k = 0; k < 8; ++k) {
        const int g = 8 * as + k;
        s += dot4(ld4s(&H_s[hQ(am, g)]), ld4s(&xb_s[4 * g]));
      }
      s += __shfl_xor(s, 1, 64);
      if (as == 0) lam_s[am] = s;
    }
    __syncthreads();
    {
      f4 u = {0.f, 0.f, 0.f, 0.f};
#pragma unroll
      for (int k = 0; k < 8; ++k) {
        const int m = 32 * w + 8 * bc + k;
        u += ld4s(&H_s[hQ(m, bg)]) * lam_s[m];
      }
      u += shx4(u, 16); u += shx4(u, 32);
      if (l < 16) st4s(&part_s[w][4 * bg], u);
    }
    __syncthreads();
    if (t < 64) {
      const float u = part_s[0][t] + part_s[1][t] + part_s[2][t] + part_s[3][t];
      float ss = u * u;
#pragma unroll
      for (int o = 1; o <= 32; o <<= 1) ss += __shfl_xor(ss, o, 64);
      xb_s[t] = u / (sqrtf(ss) + 1e-12f);
    }
    __syncthreads();
  }
  // ---- tau = 0.9 / (||H v|| + 1e-6) ----
  {
    float s = 0.f;
#pragma unroll
    for (int k = 0; k < 8; ++k) {
      const int g = 8 * as + k;
      s += dot4(ld4s(&H_s[hQ(am, g)]), ld4s(&xb_s[4 * g]));
    }
    s += __shfl_xor(s, 1, 64);
    if (as == 0) lam_s[am] = s;
  }
  __syncthreads();
  if (t < 64) {
    const float a = lam_s[t], bb = lam_s[t + 64];
    float ss = a * a + bb * bb;
#pragma unroll
    for (int o = 1; o <= 32; o <<= 1) ss += __shfl_xor(ss, o, 64);
    if (t == 0) tau_sh = 0.9f / (sqrtf(ss) + 1e-6f);
  }
  __syncthreads();
  const float tau = tau_sh;

  // ---- M = I + tau*P (registers) ----
#pragma unroll
  for (int jj = 0; jj < 16; ++jj)
    M[jj] = tau * M[jj] + ((16 * cc + jj == ci) ? 1.0f : 0.0f);

  // ---- Gauss-Jordan inversion in registers (SPD, pivots >= 1) ----
  if (ci == 0) {
#pragma unroll
    for (int jj = 0; jj < 16; ++jj) buf2[0][16 * cc + jj] = M[jj];
  }
  __syncthreads();
#pragma unroll
  for (int k = 0; k < 64; ++k) {
    const int kb = k & 1;
    const int kc = k >> 4;   // col-slice owner of column k
    const float d = 1.0f / buf2[kb][k];
    f4 rv[4];
#pragma unroll
    for (int u = 0; u < 4; ++u) rv[u] = ld4s(&buf2[kb][16 * cc + 4 * u]);
    const float f = __shfl(M[k & 15], (l & 60) | kc, 64);  // M[i][k], pre-update
    if (ci == k) {
#pragma unroll
      for (int jj = 0; jj < 16; ++jj) M[jj] = rv[jj >> 2][jj & 3] * d;
      if (cc == kc) M[k & 15] = d;
    } else {
#pragma unroll
      for (int jj = 0; jj < 16; ++jj)
        M[jj] = fmaf(-f, rv[jj >> 2][jj & 3] * d, M[jj]);
      if (cc == kc) M[k & 15] = -f * d;
    }
    if (k < 63 && ci == k + 1) {
#pragma unroll
      for (int jj = 0; jj < 16; ++jj) buf2[1 - kb][16 * cc + jj] = M[jj];
    }
    __syncthreads();
  }

  // ---- c0 = tau * (Minv q) ----
  float c0;
  {
    float acc = 0.f;
#pragma unroll
    for (int u = 0; u < 4; ++u) {
      const f4 qv = ld4s(&q_s[16 * cc + 4 * u]);
      acc = fmaf(M[4 * u + 0], qv.x, acc);
      acc = fmaf(M[4 * u + 1], qv.y, acc);
      acc = fmaf(M[4 * u + 2], qv.z, acc);
      acc = fmaf(M[4 * u + 3], qv.w, acc);
    }
    acc += __shfl_xor(acc, 1, 64);
    acc += __shfl_xor(acc, 2, 64);
    c0 = tau * acc;
  }

  // ---- PDHG (50 iters), 4 barriers/iter ----
  if (t < 64) { xb_s[t] = 0.f; xp_s[t] = 0.f; }
  float lam = 0.f, xpr = 0.f;
  const float br = b_s[am];
  __syncthreads();

  for (int it = 0; it < 50; ++it) {
    // A: lam = relu(lam - tau*(H xbar + b))   [2 lanes/row, 1 shfl]
    {
      float s = 0.f;
#pragma unroll
      for (int k = 0; k < 8; ++k) {
        const int g = 8 * as + k;
        s += dot4(ld4s(&H_s[hQ(am, g)]), ld4s(&xb_s[4 * g]));
      }
      s += __shfl_xor(s, 1, 64);
      lam = fmaxf(lam - tau * (s + br), 0.f);
      if (as == 0) lam_s[am] = lam;
    }
    __syncthreads();
    // B: per-wave partials of H^T lam
    {
      f4 u = {0.f, 0.f, 0.f, 0.f};
#pragma unroll
      for (int k = 0; k < 8; ++k) {
        const int m = 32 * w + 8 * bc + k;
        u += ld4s(&H_s[hQ(m, bg)]) * lam_s[m];
      }
      u += shx4(u, 16); u += shx4(u, 32);
      if (l < 16) st4s(&part_s[w][4 * bg], u);
    }
    __syncthreads();
    // C1: rhs = xp + tau * (sum of wave partials)   [64 threads]
    if (t < 64) {
      const float uu = part_s[0][t] + part_s[1][t] + part_s[2][t] + part_s[3][t];
      rhs_s[t] = xp_s[t] + tau * uu;
    }
    __syncthreads();
    // C2: xn = Minv*rhs - c0   [register Minv, broadcast rhs reads]
    {
      float acc = 0.f;
#pragma unroll
      for (int u = 0; u < 4; ++u) {
        const f4 rv = ld4s(&rhs_s[16 * cc + 4 * u]);
        acc = fmaf(M[4 * u + 0], rv.x, acc);
        acc = fmaf(M[4 * u + 1], rv.y, acc);
        acc = fmaf(M[4 * u + 2], rv.z, acc);
        acc = fmaf(M[4 * u + 3], rv.w, acc);
      }
      acc += __shfl_xor(acc, 1, 64);
      acc += __shfl_xor(acc, 2, 64);
      if (cc == 0) {
        const float xn = acc - c0;
        xp_s[ci] = xn;
        xb_s[ci] = 2.f * xn - xpr;
        xpr = xn;
      }
    }
    __syncthreads();
  }

  if (cc == 0) {
    const size_t oi = (size_t)blockIdx.x * NQP + ci;
    if (isf) ((float*)xs)[oi] = xpr;
    else     ((u16*)xs)[oi]   = f2b(xpr);
  }
}

// ---------------------------------------------------------------------------
extern "C" void kernel_launch(void* const* d_in, const int* in_sizes, int n_in,
                              void* d_out, int out_size, void* d_ws, size_t ws_size,
                              hipStream_t stream) {
  const void* x  = d_in[0];
  const void* W1 = d_in[1];
  const void* b1 = d_in[2];
  const void* W2 = d_in[3];
  const void* b2 = d_in[4];
  const void* W3 = d_in[5];
  const void* b3 = d_in[6];

  char* ws = (char*)d_ws;
  size_t off = 0;
  auto take = [&](size_t bytes) -> char* {
    char* r = ws + off;
    off += (bytes + 255) & ~(size_t)255;
    return r;
  };
  int*   flag = (int*)take(256);
  float* bf1  = (float*)take(1024 * 4);
  float* bf2  = (float*)take(1024 * 4);
  float* bf3  = (float*)take((size_t)NOUT * 4);
  u16*   W3t  = (u16*)take((size_t)NOUTP * 1024 * 2);
  u16*   h2hi = (u16*)take(1024ull * 1024 * 2);
  char*  region = take(1024ull * NOUT * 4);   // outf, overlaid below
  float* outf = (float*)region;
  u16* xb   = (u16*)(region + 0);                 // 1 MB
  u16* W1t  = (u16*)(region + (1u << 20));        // 1 MB
  u16* W2t  = (u16*)(region + (2u << 20));        // 2 MB
  u16* h1hi = (u16*)(region + (4u << 20));        // 2 MB
  u16* h1lo = (u16*)(region + (6u << 20));        // 2 MB
  (void)ws_size; (void)in_sizes; (void)n_in; (void)out_size;

  detect_dtype<<<dim3(1), 256, 0, stream>>>((const u16*)W1, flag);

  convert_bf16<<<dim3(512), 256, 0, stream>>>(x, xb, 1024 * 512, flag);
  conv_biases<<<dim3(49), 256, 0, stream>>>(b1, b2, b3, bf1, bf2, bf3, flag);
  transpose_all<<<dim3(392, 32), 256, 0, stream>>>(W1, W2, W3, W1t, W2t, W3t, flag);

  // GEMM1: h1 = relu(x @ W1 + b1), split store (hi+lo) — 64x64 tiles, 256 blocks
  gemm_bt64<0, false><<<dim3(16, 16), 256, 0, stream>>>(xb, nullptr, W1t, bf1,
                                                        h1hi, h1lo, 1024, 512);
  // GEMM2: h2 = relu((h1hi+h1lo) @ W2 + b2), hi only — 64x64 tiles, 256 blocks
  gemm_bt64<2, true><<<dim3(16, 16), 256, 0, stream>>>(h1hi, h1lo, W2t, bf2,
                                                       h2hi, nullptr, 1024, 1024);
  // GEMM3: out = h2hi @ W3 + b3 (single chain, f32 out)
  gemm_bt<1, false><<<dim3(NOUTP / 128, 8), 256, 0, stream>>>(h2hi, nullptr, W3t, bf3,
                                                              nullptr, nullptr, outf, 1024, NOUT, 1024);
  qp_solve<<<dim3(1024), 256, 0, stream>>>(outf, d_out, flag);
}